// Round 8
// baseline (5882.551 us; speedup 1.0000x reference)
//
#include <hip/hip_runtime.h>
#include <stdint.h>

typedef unsigned short u16;

#define B_ 4
#define H_ 8
#define T_ 2048
#define C_ 256
#define PAD 258  /* f32 words per LDS row: 2-way-max (free) bank pattern for all uses */

// Pure-VALU, pure-f32 reference kernel; identical math to rounds 5/6 (audited).
// ONLY change vs round 6: output stored as FLOAT32 (the reference's output
// dtype per the harness contract), not bf16.
__global__ __launch_bounds__(256) void k_ref(const float* __restrict__ rp,
                                             const float* __restrict__ E,
                                             const float* __restrict__ Q,
                                             float* __restrict__ out) {
  __shared__ float rps[32 * PAD];  // staged rp u-chunk; reused as z8 after loop
  __shared__ float qr8[8 * PAD];   // QR row t, all 8 heads
  __shared__ float s8[8 * 33];     // S chunk: [h][u]
  __shared__ float rpt[C_];        // rp row t

  const int t = blockIdx.x;
  const int b = blockIdx.y;
  const int tid = threadIdx.x;

  const float* rpb = rp + (size_t)b * T_ * C_;

  rpt[tid] = rpb[(size_t)t * C_ + tid];
  __syncthreads();

  // ---- QR[h][j] = sum_i rp[t][i] * Q[h][i][j]  (thread j, coalesced Q cols)
  for (int h = 0; h < H_; ++h) {
    const float* qh = Q + (size_t)h * C_ * C_ + tid;
    float acc = 0.f;
    for (int i = 0; i < C_; ++i) acc += rpt[i] * qh[(size_t)i * C_];
    qr8[h * PAD + tid] = acc;
  }

  float zreg[H_];
  #pragma unroll
  for (int h = 0; h < H_; ++h) zreg[h] = 0.f;

  const int sh = tid >> 5;  // head for S phase
  const int su = tid & 31;  // u within chunk for S phase

  for (int u0 = 0; u0 <= t; u0 += 32) {
    __syncthreads();  // previous Z phase done before rps/s8 overwrite
    // ---- stage 32 rp rows (coalesced; row c written by all 256 threads)
    for (int c = 0; c < 32; ++c)
      rps[c * PAD + tid] = rpb[(size_t)(u0 + c) * C_ + tid];
    __syncthreads();

    // ---- S: s8[h][u] = sum_j qr8[h][j] * rp[u0+u][j]; causal zero for u > t
    float s = 0.f;
    if (u0 + su <= t) {
      const float2* qrow = (const float2*)(qr8 + sh * PAD);
      const float2* rrow = (const float2*)(rps + su * PAD);
      for (int j = 0; j < C_ / 2; ++j) {
        float2 a = qrow[j], c = rrow[j];
        s += a.x * c.x + a.y * c.y;
      }
    }
    s8[sh * 33 + su] = s;
    __syncthreads();

    // ---- Z: zreg[h] += sum_u s8[h][u] * rp[u0+u][j=tid]
    #pragma unroll
    for (int h = 0; h < H_; ++h) {
      float acc = zreg[h];
      const float* srow = s8 + h * 33;
      for (int u = 0; u < 32; ++u) acc += srow[u] * rps[u * PAD + tid];
      zreg[h] = acc;
    }
  }
  __syncthreads();

  // ---- z8 overwrites rps region (dead now)
  float* z8 = rps;
  #pragma unroll
  for (int h = 0; h < H_; ++h) z8[h * PAD + tid] = zreg[h];
  __syncthreads();

  // ---- O[t][i=tid] = sum_h sum_j z8[h][j] * E[h][i][j]
  float o = 0.f;
  for (int h = 0; h < H_; ++h) {
    const float* eh = E + ((size_t)h * C_ + tid) * C_;
    const float* zrow = z8 + h * PAD;
    for (int j = 0; j < C_; ++j) o += zrow[j] * eh[j];
  }

  out[((size_t)b * T_ + t) * C_ + tid] = o;  // FLOAT32 store
}

extern "C" void kernel_launch(void* const* d_in, const int* in_sizes, int n_in,
                              void* d_out, int out_size, void* d_ws, size_t ws_size,
                              hipStream_t stream) {
  (void)d_ws; (void)ws_size; (void)out_size;
  // Select inputs by SIZE (robust to d_in ordering):
  //   r_prime: 2,097,152 elements (unique); E, Q: 524,288 each, E before Q
  //   under both insertion order (r_prime,E,Q) and sorted order (E,Q,r_prime).
  const float* rp_f = nullptr;
  const float* sm[2] = {nullptr, nullptr};
  int ns = 0;
  for (int i = 0; i < n_in; ++i) {
    if (in_sizes[i] == 2097152) {
      rp_f = (const float*)d_in[i];
    } else if (ns < 2) {
      sm[ns++] = (const float*)d_in[i];
    }
  }
  const float* E_f = sm[0];
  const float* Q_f = sm[1];
  k_ref<<<dim3(T_, B_), 256, 0, stream>>>(rp_f, E_f, Q_f, (float*)d_out);
}

// Round 9
// 370.546 us; speedup vs baseline: 15.8754x; 15.8754x over previous
//
#include <hip/hip_runtime.h>
#include <stdint.h>

typedef unsigned short u16;
typedef __attribute__((ext_vector_type(4))) float f32x4;
typedef __attribute__((ext_vector_type(4))) uint32_t u32x4;
typedef __attribute__((ext_vector_type(8))) __bf16 bf16x8;

#define B_ 4
#define H_ 8
#define T_ 2048
#define C_ 256

#define XP 528  /* x_l pitch: 256 bf16 + 16B rotation -> 2-way max on b128 reads */
#define SP 144  /* s_l pitch:  64 bf16 + 16B rotation */

static __device__ __forceinline__ f32x4 mfma16(u32x4 a, u32x4 b, f32x4 c) {
  union { u32x4 u; bf16x8 b; } A, Bb;
  A.u = a; Bb.u = b;
  return __builtin_amdgcn_mfma_f32_16x16x32_bf16(A.b, Bb.b, c, 0, 0, 0);
}
static __device__ __forceinline__ u16 f2b(float f) {
  union { __bf16 h; u16 u; } r; r.h = (__bf16)f; return r.u;
}

// ---------------- zero-fill d_out (f32) ----------------
__global__ void k_zero(float* __restrict__ p) {
  ((f32x4*)p)[blockIdx.x * 256 + threadIdx.x] = (f32x4)0.f;
}

// ---------------- f32 -> bf16 bulk convert ----------------
__global__ void k_f2b(const float* __restrict__ s, u16* __restrict__ d) {
  int idx = blockIdx.x * 256 + threadIdx.x;
  f32x4 v = ((const f32x4*)s)[idx];
  union { u16 h[4]; uint64_t q; } p;
  #pragma unroll
  for (int j = 0; j < 4; ++j) p.h[j] = f2b(v[j]);
  ((uint64_t*)d)[idx] = p.q;
}

// ---------------- Q[h][i][j] f32 -> Qt[h][j][i] bf16 ----------------
__global__ void k_qt(const float* __restrict__ q, u16* __restrict__ qt) {
  __shared__ u16 l[64][72];
  const int h = blockIdx.x, i0 = blockIdx.y * 64, j0 = blockIdx.z * 64;
  const int tj = threadIdx.x & 63, tq = threadIdx.x >> 6;
  const float* qh = q + (size_t)h * C_ * C_;
  #pragma unroll
  for (int r = 0; r < 16; ++r) {
    int i = r * 4 + tq;
    l[i][tj] = f2b(qh[(size_t)(i0 + i) * C_ + j0 + tj]);
  }
  __syncthreads();
  u16* qth = qt + (size_t)h * C_ * C_;
  #pragma unroll
  for (int r = 0; r < 16; ++r) {
    int j = r * 4 + tq;
    qth[(size_t)(j0 + j) * C_ + i0 + tj] = l[tj][j];
  }
}

// ---------------- rp[b][t][i] f32 -> rpT[b][i][t] bf16 ----------------
__global__ void k_rpt(const float* __restrict__ rp, u16* __restrict__ rt) {
  __shared__ u16 l[64][72];
  const int t0 = blockIdx.x * 64, i0 = blockIdx.y * 64, b = blockIdx.z;
  const int tj = threadIdx.x & 63, tq = threadIdx.x >> 6;
  const float* src = rp + (size_t)b * T_ * C_;
  #pragma unroll
  for (int r = 0; r < 16; ++r) {
    int tl = r * 4 + tq;
    l[tl][tj] = f2b(src[(size_t)(t0 + tl) * C_ + i0 + tj]);
  }
  __syncthreads();
  u16* dst = rt + (size_t)b * C_ * T_;
  #pragma unroll
  for (int r = 0; r < 16; ++r) {
    int il = r * 4 + tq;
    dst[(size_t)(i0 + il) * T_ + t0 + tj] = l[tj][il];
  }
}

// ---------------- fused main ----------------
// Block = (pair pk, b, head-group hg). Processes tiles {63-pk, pk} (each 32 t-rows)
// for heads {hg, hg+4}: QR -> causal S -> Z += S*rp -> O = Z*E^T, f32 LDS accum
// over the 2 heads, then f32 atomicAdd into d_out. Every block does exactly 33
// u-iters per head -> perfect static load balance across 512 blocks (2/CU).
__global__ __launch_bounds__(256, 2) void k_main(const u16* __restrict__ rbf,
                                                 const u16* __restrict__ rpT,
                                                 const u16* __restrict__ qtb,
                                                 const u16* __restrict__ ebf,
                                                 float* __restrict__ out) {
  __shared__ __align__(16) float oc[32 * C_];   // 32KB f32 output accumulator
  __shared__ __align__(16) char x_l[32 * XP];   // QR / Z bounce (bf16)
  __shared__ __align__(16) char s_l[32 * SP];   // S tile (bf16)

  const int pk = blockIdx.x, b = blockIdx.y, hg = blockIdx.z;
  const int tid = threadIdx.x, lane = tid & 63, v = tid >> 6;
  const int l15 = lane & 15, lq = lane >> 4;

  const u16* rpb = rbf + (size_t)b * T_ * C_;
  const u16* rtb = rpT + (size_t)b * C_ * T_;

  for (int half = 0; half < 2; ++half) {
    const int tile = half ? pk : 63 - pk;  // long tile first
    const int t0 = tile * 32;
    const int nu = t0 / 64 + 1;

    {
      f32x4* ov = (f32x4*)oc;
      #pragma unroll
      for (int e = 0; e < 8; ++e) ov[tid * 8 + e] = (f32x4)0.f;
    }
    __syncthreads();

    for (int hh = 0; hh < 2; ++hh) {
      const int h = hg + 4 * hh;
      const u16* qth = qtb + (size_t)h * C_ * C_;
      const u16* eh  = ebf + (size_t)h * C_ * C_;

      // ---- QR prologue: QR[32 t][256 j]; wave v owns j in [64v, 64v+64) ----
      {
        u32x4 am[2][8];
        #pragma unroll
        for (int m = 0; m < 2; ++m) {
          const u16* ar = rpb + (size_t)(t0 + 16 * m + l15) * C_ + 8 * lq;
          #pragma unroll
          for (int k = 0; k < 8; ++k) am[m][k] = *(const u32x4*)(ar + 32 * k);
        }
        #pragma unroll
        for (int n = 0; n < 4; ++n) {
          const int jn = 16 * (4 * v + n);
          const u16* qr_ = qth + (size_t)(jn + l15) * C_ + 8 * lq;
          f32x4 qacc[2];
          qacc[0] = (f32x4)0.f; qacc[1] = (f32x4)0.f;
          #pragma unroll
          for (int kk = 0; kk < 8; ++kk) {
            u32x4 bq = *(const u32x4*)(qr_ + 32 * kk);
            qacc[0] = mfma16(am[0][kk], bq, qacc[0]);
            qacc[1] = mfma16(am[1][kk], bq, qacc[1]);
          }
          #pragma unroll
          for (int m = 0; m < 2; ++m)
            #pragma unroll
            for (int r = 0; r < 4; ++r)
              *(u16*)(x_l + (size_t)(16 * m + 4 * lq + r) * XP +
                      (jn + l15) * 2) = f2b(qacc[m][r]);
        }
      }
      __syncthreads();

      u32x4 qa[2][8];
      #pragma unroll
      for (int m = 0; m < 2; ++m)
        #pragma unroll
        for (int kk = 0; kk < 8; ++kk)
          qa[m][kk] = *(const u32x4*)(x_l + (size_t)(16 * m + l15) * XP +
                                      64 * kk + 16 * lq);
      // (x_l next written in epilogue, always after >=1 u-loop barrier)

      f32x4 zacc[2][4];
      #pragma unroll
      for (int m = 0; m < 2; ++m)
        #pragma unroll
        for (int n = 0; n < 4; ++n) zacc[m][n] = (f32x4)0.f;

      for (int ut = 0; ut < nu; ++ut) {
        const int u0 = ut * 64;
        // ---- S: S[32 t][64 u]; wave v owns u in [16v, 16v+16) ----
        f32x4 sacc[2];
        sacc[0] = (f32x4)0.f; sacc[1] = (f32x4)0.f;
        {
          const u16* br = rpb + (size_t)(u0 + 16 * v + l15) * C_ + 8 * lq;
          #pragma unroll
          for (int kk = 0; kk < 8; ++kk) {
            u32x4 bs = *(const u32x4*)(br + 32 * kk);
            sacc[0] = mfma16(qa[0][kk], bs, sacc[0]);
            sacc[1] = mfma16(qa[1][kk], bs, sacc[1]);
          }
        }
        if (ut == nu - 1) {  // causal mask (diagonal u-tile)
          #pragma unroll
          for (int m = 0; m < 2; ++m)
            #pragma unroll
            for (int r = 0; r < 4; ++r) {
              int tg = t0 + 16 * m + 4 * lq + r;
              int ug = u0 + 16 * v + l15;
              if (ug > tg) sacc[m][r] = 0.f;
            }
        }
        #pragma unroll
        for (int m = 0; m < 2; ++m)
          #pragma unroll
          for (int r = 0; r < 4; ++r)
            *(u16*)(s_l + (size_t)(16 * m + 4 * lq + r) * SP +
                    (16 * v + l15) * 2) = f2b(sacc[m][r]);
        __syncthreads();

        // ---- Z: zacc[32 t][j in 64v..64v+64) += S * rp ----
        u32x4 sa[2][2];
        #pragma unroll
        for (int m = 0; m < 2; ++m)
          #pragma unroll
          for (int kk = 0; kk < 2; ++kk)
            sa[m][kk] = *(const u32x4*)(s_l + (size_t)(16 * m + l15) * SP +
                                        64 * kk + 16 * lq);
        #pragma unroll
        for (int kk = 0; kk < 2; ++kk)
          #pragma unroll
          for (int n = 0; n < 4; ++n) {
            u32x4 vb = *(const u32x4*)(rtb + (size_t)(64 * v + 16 * n + l15) * T_ +
                                       u0 + 32 * kk + 8 * lq);
            zacc[0][n] = mfma16(sa[0][kk], vb, zacc[0][n]);
            zacc[1][n] = mfma16(sa[1][kk], vb, zacc[1][n]);
          }
        __syncthreads();  // s_l consumed before next iter overwrite
      }

      // ---- epilogue: O = Z * E^T; bounce Z via x_l ----
      #pragma unroll
      for (int m = 0; m < 2; ++m)
        #pragma unroll
        for (int n = 0; n < 4; ++n)
          #pragma unroll
          for (int r = 0; r < 4; ++r)
            *(u16*)(x_l + (size_t)(16 * m + 4 * lq + r) * XP +
                    (64 * v + 16 * n + l15) * 2) = f2b(zacc[m][n][r]);
      __syncthreads();
      {
        u32x4 za[2][8];
        #pragma unroll
        for (int m = 0; m < 2; ++m)
          #pragma unroll
          for (int kk = 0; kk < 8; ++kk)
            za[m][kk] = *(const u32x4*)(x_l + (size_t)(16 * m + l15) * XP +
                                        64 * kk + 16 * lq);
        f32x4 oa[2][4];
        #pragma unroll
        for (int m = 0; m < 2; ++m)
          #pragma unroll
          for (int n = 0; n < 4; ++n) oa[m][n] = (f32x4)0.f;
        #pragma unroll
        for (int n = 0; n < 4; ++n) {
          const u16* er = eh + (size_t)(64 * v + 16 * n + l15) * C_ + 8 * lq;
          #pragma unroll
          for (int kk = 0; kk < 8; ++kk) {
            u32x4 eb = *(const u32x4*)(er + 32 * kk);
            oa[0][n] = mfma16(za[0][kk], eb, oa[0][n]);
            oa[1][n] = mfma16(za[1][kk], eb, oa[1][n]);
          }
        }
        // per-thread-disjoint (t,i) -> plain adds into LDS f32
        #pragma unroll
        for (int m = 0; m < 2; ++m)
          #pragma unroll
          for (int n = 0; n < 4; ++n)
            #pragma unroll
            for (int r = 0; r < 4; ++r)
              oc[(size_t)(16 * m + 4 * lq + r) * C_ + 64 * v + 16 * n + l15] +=
                  oa[m][n][r];
      }
      __syncthreads();  // za reads + oc adds done before next head / writeout
    }

    // ---- writeout: f32 atomicAdd (4 hg-blocks contribute per element) ----
    {
      float* ob = out + ((size_t)b * T_ + t0) * C_;
      #pragma unroll
      for (int e = 0; e < 32; ++e)
        atomicAdd(ob + e * 256 + tid, oc[e * 256 + tid]);
    }
    __syncthreads();  // oc free for next half
  }
}

extern "C" void kernel_launch(void* const* d_in, const int* in_sizes, int n_in,
                              void* d_out, int out_size, void* d_ws, size_t ws_size,
                              hipStream_t stream) {
  (void)ws_size; (void)out_size;
  // Size-based input selection (robust to d_in ordering):
  //   r_prime: 2,097,152 elems (unique); E, Q: 524,288 each, E before Q.
  const float* rp_f = nullptr;
  const float* sm[2] = {nullptr, nullptr};
  int ns = 0;
  for (int i = 0; i < n_in; ++i) {
    if (in_sizes[i] == 2097152) {
      rp_f = (const float*)d_in[i];
    } else if (ns < 2) {
      sm[ns++] = (const float*)d_in[i];
    }
  }
  const float* E_f = sm[0];
  const float* Q_f = sm[1];

  // ws: rbf bf16 [0,4M) | rpT bf16 [4M,8M) | Qt bf16 [8M,9M) | Ebf bf16 [9M,10M)
  const size_t MB = 1024 * 1024;
  u16* rbf = (u16*)d_ws;
  u16* rpT = (u16*)((char*)d_ws + 4 * MB);
  u16* qtb = (u16*)((char*)d_ws + 8 * MB);
  u16* ebf = (u16*)((char*)d_ws + 9 * MB);
  float* outf = (float*)d_out;

  k_zero<<<2048, 256, 0, stream>>>(outf);
  k_f2b<<<2048, 256, 0, stream>>>(rp_f, rbf);
  k_f2b<<<512, 256, 0, stream>>>(E_f, ebf);
  k_qt<<<dim3(8, 4, 4), 256, 0, stream>>>(Q_f, qtb);
  k_rpt<<<dim3(32, 4, 4), 256, 0, stream>>>(rp_f, rpT);
  k_main<<<dim3(32, 4, 4), 256, 0, stream>>>(rbf, rpT, qtb, ebf, outf);
}

// Round 10
// 217.606 us; speedup vs baseline: 27.0330x; 1.7028x over previous
//
#include <hip/hip_runtime.h>
#include <stdint.h>

typedef unsigned short u16;
typedef __attribute__((ext_vector_type(4))) float f32x4;
typedef __attribute__((ext_vector_type(4))) uint32_t u32x4;
typedef __attribute__((ext_vector_type(8))) __bf16 bf16x8;

#define B_ 4
#define H_ 8
#define T_ 2048
#define C_ 256
#define NCH 32   /* 64-row chunks per b */
#define XP 528   /* 64-row QR/Z LDS pitch (bytes) */
#define SP 144   /* 64-row S LDS pitch (bytes) */

static __device__ __forceinline__ f32x4 mfma16(u32x4 a, u32x4 b, f32x4 c) {
  union { u32x4 u; bf16x8 b; } A, Bb;
  A.u = a; Bb.u = b;
  return __builtin_amdgcn_mfma_f32_16x16x32_bf16(A.b, Bb.b, c, 0, 0, 0);
}
static __device__ __forceinline__ u16 f2b(float f) {
  union { __bf16 h; u16 u; } r; r.h = (__bf16)f; return r.u;
}

__global__ void k_zero(float* __restrict__ p) {
  ((f32x4*)p)[blockIdx.x * 256 + threadIdx.x] = (f32x4)0.f;
}

__global__ void k_f2b(const float* __restrict__ s, u16* __restrict__ d) {
  int idx = blockIdx.x * 256 + threadIdx.x;
  f32x4 v = ((const f32x4*)s)[idx];
  union { u16 h[4]; uint64_t q; } p;
  #pragma unroll
  for (int j = 0; j < 4; ++j) p.h[j] = f2b(v[j]);
  ((uint64_t*)d)[idx] = p.q;
}

// Q[h][i][j] f32 -> Qt[h][j][i] bf16
__global__ void k_qt(const float* __restrict__ q, u16* __restrict__ qt) {
  __shared__ u16 l[64][72];
  const int h = blockIdx.x, i0 = blockIdx.y * 64, j0 = blockIdx.z * 64;
  const int tj = threadIdx.x & 63, tq = threadIdx.x >> 6;
  const float* qh = q + (size_t)h * C_ * C_;
  #pragma unroll
  for (int r = 0; r < 16; ++r) {
    int i = r * 4 + tq;
    l[i][tj] = f2b(qh[(size_t)(i0 + i) * C_ + j0 + tj]);
  }
  __syncthreads();
  u16* qth = qt + (size_t)h * C_ * C_;
  #pragma unroll
  for (int r = 0; r < 16; ++r) {
    int j = r * 4 + tq;
    qth[(size_t)(j0 + j) * C_ + i0 + tj] = l[tj][j];
  }
}

// rp[b][t][i] f32 -> rpT[b][i][t] bf16
__global__ void k_rpt(const float* __restrict__ rp, u16* __restrict__ rt) {
  __shared__ u16 l[64][72];
  const int t0 = blockIdx.x * 64, i0 = blockIdx.y * 64, b = blockIdx.z;
  const int tj = threadIdx.x & 63, tq = threadIdx.x >> 6;
  const float* src = rp + (size_t)b * T_ * C_;
  #pragma unroll
  for (int r = 0; r < 16; ++r) {
    int tl = r * 4 + tq;
    l[tl][tj] = f2b(src[(size_t)(t0 + tl) * C_ + i0 + tj]);
  }
  __syncthreads();
  u16* dst = rt + (size_t)b * C_ * T_;
  #pragma unroll
  for (int r = 0; r < 16; ++r) {
    int il = r * 4 + tq;
    dst[(size_t)(i0 + il) * T_ + t0 + tj] = l[tj][il];
  }
}

// G_excl[b][k][i][j] = sum_{u < 64k} rp[b][u][i]*rp[b][u][j]  (bf16 store,
// f32 register prefix). Block = (j-strip of 32, b); wave v owns i-quarter.
__global__ __launch_bounds__(256) void k_gram(const u16* __restrict__ rpT,
                                              u16* __restrict__ G) {
  const int s = blockIdx.x, b = blockIdx.y;
  const int tid = threadIdx.x, lane = tid & 63, v = tid >> 6;
  const int l15 = lane & 15, lq = lane >> 4;
  const u16* rtb = rpT + (size_t)b * C_ * T_;

  f32x4 acc[4][2];
  #pragma unroll
  for (int m = 0; m < 4; ++m)
    #pragma unroll
    for (int n = 0; n < 2; ++n) acc[m][n] = (f32x4)0.f;

  for (int k = 0; k < NCH; ++k) {
    // store exclusive prefix for chunk k
    u16* gk = G + (size_t)(b * NCH + k) * C_ * C_;
    #pragma unroll
    for (int m = 0; m < 4; ++m)
      #pragma unroll
      for (int n = 0; n < 2; ++n)
        #pragma unroll
        for (int r = 0; r < 4; ++r)
          gk[(size_t)(64 * v + 16 * m + 4 * lq + r) * C_ + 32 * s + 16 * n + l15] =
              f2b(acc[m][n][r]);
    // accumulate chunk k
    u32x4 am[4][2], bn[2][2];
    #pragma unroll
    for (int m = 0; m < 4; ++m)
      #pragma unroll
      for (int kk = 0; kk < 2; ++kk)
        am[m][kk] = *(const u32x4*)(rtb + (size_t)(64 * v + 16 * m + l15) * T_ +
                                    64 * k + 32 * kk + 8 * lq);
    #pragma unroll
    for (int n = 0; n < 2; ++n)
      #pragma unroll
      for (int kk = 0; kk < 2; ++kk)
        bn[n][kk] = *(const u32x4*)(rtb + (size_t)(32 * s + 16 * n + l15) * T_ +
                                    64 * k + 32 * kk + 8 * lq);
    #pragma unroll
    for (int m = 0; m < 4; ++m)
      #pragma unroll
      for (int n = 0; n < 2; ++n)
        #pragma unroll
        for (int kk = 0; kk < 2; ++kk)
          acc[m][n] = mfma16(am[m][kk], bn[n][kk], acc[m][n]);
  }
}

// Fused main: per (64-row tile, b, hg) over heads {hg, hg+4}:
//   QR = rp*Qt -> Z = QR*G_excl + masked(QR*rp^T)*rp -> O += Z*E^T (f32 regs),
// then one atomicAdd pass. Uniform work per block; 3 barriers per head.
__global__ __launch_bounds__(256, 2) void k_main(const u16* __restrict__ rbf,
                                                 const u16* __restrict__ rpT,
                                                 const u16* __restrict__ qtb,
                                                 const u16* __restrict__ ebf,
                                                 const u16* __restrict__ G,
                                                 float* __restrict__ out) {
  __shared__ __align__(16) char x_l[64 * XP];
  __shared__ __align__(16) char z_l[64 * XP];
  __shared__ __align__(16) char s_l[64 * SP];

  const int tile = blockIdx.x, b = blockIdx.y, hg = blockIdx.z;
  const int t0 = tile * 64;
  const int tid = threadIdx.x, lane = tid & 63, v = tid >> 6;
  const int l15 = lane & 15, lq = lane >> 4;

  const u16* rpb = rbf + (size_t)b * T_ * C_;
  const u16* rtb = rpT + (size_t)b * C_ * T_;
  const u16* gt  = G + (size_t)(b * NCH + tile) * C_ * C_;

  f32x4 oa[4][4];
  #pragma unroll
  for (int m = 0; m < 4; ++m)
    #pragma unroll
    for (int n = 0; n < 4; ++n) oa[m][n] = (f32x4)0.f;

  for (int hh = 0; hh < 2; ++hh) {
    const int h = hg + 4 * hh;
    const u16* qth = qtb + (size_t)h * C_ * C_;
    const u16* eh  = ebf + (size_t)h * C_ * C_;

    // ---- QR[64 t][256 j]; wave v owns j in [64v, 64v+64) ----
    #pragma unroll
    for (int mh = 0; mh < 2; ++mh) {
      u32x4 am[2][8];
      #pragma unroll
      for (int mq = 0; mq < 2; ++mq)
        #pragma unroll
        for (int kk = 0; kk < 8; ++kk)
          am[mq][kk] = *(const u32x4*)(rpb +
              (size_t)(t0 + 32 * mh + 16 * mq + l15) * C_ + 32 * kk + 8 * lq);
      #pragma unroll
      for (int n = 0; n < 4; ++n) {
        f32x4 qacc[2];
        qacc[0] = (f32x4)0.f; qacc[1] = (f32x4)0.f;
        #pragma unroll
        for (int kk = 0; kk < 8; ++kk) {
          u32x4 bq = *(const u32x4*)(qth +
              (size_t)(64 * v + 16 * n + l15) * C_ + 32 * kk + 8 * lq);
          qacc[0] = mfma16(am[0][kk], bq, qacc[0]);
          qacc[1] = mfma16(am[1][kk], bq, qacc[1]);
        }
        #pragma unroll
        for (int mq = 0; mq < 2; ++mq)
          #pragma unroll
          for (int r = 0; r < 4; ++r)
            *(u16*)(x_l + (size_t)(32 * mh + 16 * mq + 4 * lq + r) * XP +
                    (64 * v + 16 * n + l15) * 2) = f2b(qacc[mq][r]);
      }
    }
    __syncthreads();

    // ---- Z_full = QR*G (wave owns j-quarter) fused with S_loc = QR*rp^T ----
    f32x4 acc[4][4], sacc[4];
    #pragma unroll
    for (int m = 0; m < 4; ++m) {
      sacc[m] = (f32x4)0.f;
      #pragma unroll
      for (int n = 0; n < 4; ++n) acc[m][n] = (f32x4)0.f;
    }
    #pragma unroll
    for (int mp = 0; mp < 2; ++mp) {
      u32x4 qa2[2][8];
      #pragma unroll
      for (int mq = 0; mq < 2; ++mq)
        #pragma unroll
        for (int kk = 0; kk < 8; ++kk)
          qa2[mq][kk] = *(const u32x4*)(x_l +
              (size_t)(32 * mp + 16 * mq + l15) * XP + 64 * kk + 16 * lq);
      #pragma unroll
      for (int n = 0; n < 4; ++n)
        #pragma unroll
        for (int kk = 0; kk < 8; ++kk) {
          u32x4 bg = *(const u32x4*)(gt +
              (size_t)(64 * v + 16 * n + l15) * C_ + 32 * kk + 8 * lq);
          acc[2 * mp + 0][n] = mfma16(qa2[0][kk], bg, acc[2 * mp + 0][n]);
          acc[2 * mp + 1][n] = mfma16(qa2[1][kk], bg, acc[2 * mp + 1][n]);
        }
      #pragma unroll
      for (int kk = 0; kk < 8; ++kk) {
        u32x4 bs = *(const u32x4*)(rpb +
            (size_t)(t0 + 16 * v + l15) * C_ + 32 * kk + 8 * lq);
        sacc[2 * mp + 0] = mfma16(qa2[0][kk], bs, sacc[2 * mp + 0]);
        sacc[2 * mp + 1] = mfma16(qa2[1][kk], bs, sacc[2 * mp + 1]);
      }
    }
    // causal mask (local: tile-diagonal) + S write
    #pragma unroll
    for (int m = 0; m < 4; ++m)
      #pragma unroll
      for (int r = 0; r < 4; ++r) {
        int tl = 16 * m + 4 * lq + r;
        int ul = 16 * v + l15;
        float sv = (ul > tl) ? 0.f : sacc[m][r];
        *(u16*)(s_l + (size_t)tl * SP + ul * 2) = f2b(sv);
      }
    __syncthreads();

    // ---- Z_loc: acc += S * rp  (B from rpT rows, wave's j-quarter) ----
    u32x4 sa[4][2];
    #pragma unroll
    for (int m = 0; m < 4; ++m)
      #pragma unroll
      for (int kk = 0; kk < 2; ++kk)
        sa[m][kk] = *(const u32x4*)(s_l + (size_t)(16 * m + l15) * SP +
                                    64 * kk + 16 * lq);
    #pragma unroll
    for (int n = 0; n < 4; ++n)
      #pragma unroll
      for (int kk = 0; kk < 2; ++kk) {
        u32x4 vb = *(const u32x4*)(rtb +
            (size_t)(64 * v + 16 * n + l15) * T_ + t0 + 32 * kk + 8 * lq);
        #pragma unroll
        for (int m = 0; m < 4; ++m)
          acc[m][n] = mfma16(sa[m][kk], vb, acc[m][n]);
      }
    // Z write (bf16)
    #pragma unroll
    for (int m = 0; m < 4; ++m)
      #pragma unroll
      for (int n = 0; n < 4; ++n)
        #pragma unroll
        for (int r = 0; r < 4; ++r)
          *(u16*)(z_l + (size_t)(16 * m + 4 * lq + r) * XP +
                  (64 * v + 16 * n + l15) * 2) = f2b(acc[m][n][r]);
    __syncthreads();

    // ---- epilogue: oa += Z * E^T (wave owns i-quarter) ----
    #pragma unroll
    for (int mp = 0; mp < 2; ++mp) {
      u32x4 za2[2][8];
      #pragma unroll
      for (int mq = 0; mq < 2; ++mq)
        #pragma unroll
        for (int kk = 0; kk < 8; ++kk)
          za2[mq][kk] = *(const u32x4*)(z_l +
              (size_t)(32 * mp + 16 * mq + l15) * XP + 64 * kk + 16 * lq);
      #pragma unroll
      for (int n = 0; n < 4; ++n)
        #pragma unroll
        for (int kk = 0; kk < 8; ++kk) {
          u32x4 eb = *(const u32x4*)(eh +
              (size_t)(64 * v + 16 * n + l15) * C_ + 32 * kk + 8 * lq);
          oa[2 * mp + 0][n] = mfma16(za2[0][kk], eb, oa[2 * mp + 0][n]);
          oa[2 * mp + 1][n] = mfma16(za2[1][kk], eb, oa[2 * mp + 1][n]);
        }
    }
  }

  // ---- h-reduction: f32 atomics (4 hg-blocks per element) ----
  float* ob = out + ((size_t)b * T_ + t0) * C_;
  #pragma unroll
  for (int m = 0; m < 4; ++m)
    #pragma unroll
    for (int n = 0; n < 4; ++n)
      #pragma unroll
      for (int r = 0; r < 4; ++r)
        atomicAdd(ob + (size_t)(16 * m + 4 * lq + r) * C_ + 64 * v + 16 * n + l15,
                  oa[m][n][r]);
}

extern "C" void kernel_launch(void* const* d_in, const int* in_sizes, int n_in,
                              void* d_out, int out_size, void* d_ws, size_t ws_size,
                              hipStream_t stream) {
  (void)ws_size; (void)out_size;
  const float* rp_f = nullptr;
  const float* sm[2] = {nullptr, nullptr};
  int ns = 0;
  for (int i = 0; i < n_in; ++i) {
    if (in_sizes[i] == 2097152) {
      rp_f = (const float*)d_in[i];
    } else if (ns < 2) {
      sm[ns++] = (const float*)d_in[i];
    }
  }
  const float* E_f = sm[0];
  const float* Q_f = sm[1];

  // ws (26 MB): G bf16 [0,16M) | rbf [16,20M) | rpT [20,24M) | Qt [24,25M) | E [25,26M)
  const size_t MB = 1024 * 1024;
  u16* G   = (u16*)d_ws;
  u16* rbf = (u16*)((char*)d_ws + 16 * MB);
  u16* rpT = (u16*)((char*)d_ws + 20 * MB);
  u16* qtb = (u16*)((char*)d_ws + 24 * MB);
  u16* ebf = (u16*)((char*)d_ws + 25 * MB);
  float* outf = (float*)d_out;

  k_zero<<<2048, 256, 0, stream>>>(outf);
  k_f2b<<<2048, 256, 0, stream>>>(rp_f, rbf);
  k_f2b<<<512, 256, 0, stream>>>(E_f, ebf);
  k_qt<<<dim3(8, 4, 4), 256, 0, stream>>>(Q_f, qtb);
  k_rpt<<<dim3(32, 4, 4), 256, 0, stream>>>(rp_f, rpT);
  k_gram<<<dim3(8, 4), 256, 0, stream>>>(rpT, G);
  k_main<<<dim3(32, 4, 4), 256, 0, stream>>>(rbf, rpT, qtb, ebf, G, outf);
}

// Round 11
// 184.278 us; speedup vs baseline: 31.9222x; 1.1809x over previous
//
#include <hip/hip_runtime.h>
#include <stdint.h>

typedef unsigned short u16;
typedef __attribute__((ext_vector_type(4))) float f32x4;
typedef __attribute__((ext_vector_type(4))) uint32_t u32x4;
typedef __attribute__((ext_vector_type(8))) __bf16 bf16x8;

#define B_ 4
#define H_ 8
#define T_ 2048
#define C_ 256
#define NCH 32   /* 64-row chunks per b */
#define XP 528   /* QR/Z LDS pitch (bytes): 16B-rotated rows */
#define SP 144   /* S LDS pitch (bytes) */

static __device__ __forceinline__ f32x4 mfma16(u32x4 a, u32x4 b, f32x4 c) {
  union { u32x4 u; bf16x8 b; } A, Bb;
  A.u = a; Bb.u = b;
  return __builtin_amdgcn_mfma_f32_16x16x32_bf16(A.b, Bb.b, c, 0, 0, 0);
}
static __device__ __forceinline__ u16 f2b(float f) {
  union { __bf16 h; u16 u; } r; r.h = (__bf16)f; return r.u;
}

// ---- k_prep: zero(out) + rp->bf16 + rp^T + Q^T + E->bf16, one launch ----
__global__ __launch_bounds__(256) void k_prep(const float* __restrict__ rp_f,
                                              const float* __restrict__ E_f,
                                              const float* __restrict__ Q_f,
                                              u16* __restrict__ rbf,
                                              u16* __restrict__ rpT,
                                              u16* __restrict__ qtb,
                                              u16* __restrict__ ebf,
                                              float* __restrict__ outf) {
  __shared__ u16 l[64][72];
  const int r = blockIdx.x, tid = threadIdx.x;
  if (r < 512) {  // rp tile: straight bf16 + transposed bf16
    const int b = r >> 7, i0 = ((r >> 5) & 3) * 64, t0 = (r & 31) * 64;
    const int tj = tid & 63, tq = tid >> 6;
    const float* src = rp_f + (size_t)b * T_ * C_;
    u16* rb = rbf + (size_t)b * T_ * C_;
    #pragma unroll
    for (int rr = 0; rr < 16; ++rr) {
      int tl = rr * 4 + tq;
      u16 v = f2b(src[(size_t)(t0 + tl) * C_ + i0 + tj]);
      l[tl][tj] = v;
      rb[(size_t)(t0 + tl) * C_ + i0 + tj] = v;
    }
    __syncthreads();
    u16* dst = rpT + (size_t)b * C_ * T_;
    #pragma unroll
    for (int rr = 0; rr < 16; ++rr) {
      int il = rr * 4 + tq;
      dst[(size_t)(i0 + il) * T_ + t0 + tj] = l[tj][il];
    }
  } else if (r < 640) {  // Q transpose+convert
    const int q = r - 512;
    const int h = q >> 4, i0 = ((q >> 2) & 3) * 64, j0 = (q & 3) * 64;
    const int tj = tid & 63, tq = tid >> 6;
    const float* qh = Q_f + (size_t)h * C_ * C_;
    #pragma unroll
    for (int rr = 0; rr < 16; ++rr) {
      int i = rr * 4 + tq;
      l[i][tj] = f2b(qh[(size_t)(i0 + i) * C_ + j0 + tj]);
    }
    __syncthreads();
    u16* qth = qtb + (size_t)h * C_ * C_;
    #pragma unroll
    for (int rr = 0; rr < 16; ++rr) {
      int j = rr * 4 + tq;
      qth[(size_t)(j0 + j) * C_ + i0 + tj] = l[tj][j];
    }
  } else if (r < 2688) {  // zero d_out (8 MB f32)
    const int q = r - 640;
    ((f32x4*)outf)[(size_t)q * 256 + tid] = (f32x4)0.f;
  } else {  // E convert (512K elems)
    const int q = r - 2688;
    size_t idx = (size_t)q * 256 + tid;
    f32x4 v = ((const f32x4*)E_f)[idx];
    union { u16 h4[4]; uint64_t qq; } p;
    #pragma unroll
    for (int j = 0; j < 4; ++j) p.h4[j] = f2b(v[j]);
    ((uint64_t*)ebf)[idx] = p.qq;
  }
}

// ---- k_gram: G_excl[b][k][i][j] = sum_{u<64k} rp[u][i]*rp[u][j], bf16 ----
// grid (8 j-strips of 32, 4 i-strips of 64, 4 b); wave v owns 16 i-rows.
__global__ __launch_bounds__(256) void k_gram(const u16* __restrict__ rpT,
                                              u16* __restrict__ G) {
  const int js = blockIdx.x, iq = blockIdx.y, b = blockIdx.z;
  const int tid = threadIdx.x, lane = tid & 63, v = tid >> 6;
  const int l15 = lane & 15, lq = lane >> 4;
  const u16* rtb = rpT + (size_t)b * C_ * T_;
  const int irow = 64 * iq + 16 * v;

  f32x4 acc[2];
  acc[0] = (f32x4)0.f; acc[1] = (f32x4)0.f;

  for (int k = 0; k < NCH; ++k) {
    u16* gk = G + (size_t)(b * NCH + k) * C_ * C_;
    #pragma unroll
    for (int n = 0; n < 2; ++n)
      #pragma unroll
      for (int rr = 0; rr < 4; ++rr)
        gk[(size_t)(irow + 4 * lq + rr) * C_ + 32 * js + 16 * n + l15] =
            f2b(acc[n][rr]);
    u32x4 am[2], bn[2][2];
    #pragma unroll
    for (int kk = 0; kk < 2; ++kk)
      am[kk] = *(const u32x4*)(rtb + (size_t)(irow + l15) * T_ +
                               64 * k + 32 * kk + 8 * lq);
    #pragma unroll
    for (int n = 0; n < 2; ++n)
      #pragma unroll
      for (int kk = 0; kk < 2; ++kk)
        bn[n][kk] = *(const u32x4*)(rtb + (size_t)(32 * js + 16 * n + l15) * T_ +
                                    64 * k + 32 * kk + 8 * lq);
    #pragma unroll
    for (int n = 0; n < 2; ++n)
      #pragma unroll
      for (int kk = 0; kk < 2; ++kk)
        acc[n] = mfma16(am[kk], bn[n][kk], acc[n]);
  }
}

// ---- k_main: per (64-row tile, b, h): QR -> Z = QR*G + masked-local -> O=Z*E^T
// 3 barriers; Z reuses the QR LDS buffer; G/E fragments loaded once per wave.
__global__ __launch_bounds__(256, 3) void k_main(const u16* __restrict__ rbf,
                                                 const u16* __restrict__ rpT,
                                                 const u16* __restrict__ qtb,
                                                 const u16* __restrict__ ebf,
                                                 const u16* __restrict__ G,
                                                 float* __restrict__ out) {
  __shared__ __align__(16) char x_l[64 * XP];  // QR, then Z
  __shared__ __align__(16) char s_l[64 * SP];  // local S

  const int tile = blockIdx.x, b = blockIdx.y, h = blockIdx.z;
  const int t0 = tile * 64;
  const int tid = threadIdx.x, lane = tid & 63, v = tid >> 6;
  const int l15 = lane & 15, lq = lane >> 4;

  const u16* rpb = rbf + (size_t)b * T_ * C_;
  const u16* rtb = rpT + (size_t)b * C_ * T_;
  const u16* gt  = G + (size_t)(b * NCH + tile) * C_ * C_;
  const u16* qth = qtb + (size_t)h * C_ * C_;
  const u16* eh  = ebf + (size_t)h * C_ * C_;

  // ---- QR[64 t][256 j]; wave v owns j in [64v, 64v+64) ----
  #pragma unroll
  for (int mh = 0; mh < 2; ++mh) {
    u32x4 am[2][8];
    #pragma unroll
    for (int mq = 0; mq < 2; ++mq)
      #pragma unroll
      for (int kk = 0; kk < 8; ++kk)
        am[mq][kk] = *(const u32x4*)(rpb +
            (size_t)(t0 + 32 * mh + 16 * mq + l15) * C_ + 32 * kk + 8 * lq);
    #pragma unroll
    for (int n = 0; n < 4; ++n) {
      f32x4 qacc[2];
      qacc[0] = (f32x4)0.f; qacc[1] = (f32x4)0.f;
      #pragma unroll
      for (int kk = 0; kk < 8; ++kk) {
        u32x4 bq = *(const u32x4*)(qth +
            (size_t)(64 * v + 16 * n + l15) * C_ + 32 * kk + 8 * lq);
        qacc[0] = mfma16(am[0][kk], bq, qacc[0]);
        qacc[1] = mfma16(am[1][kk], bq, qacc[1]);
      }
      #pragma unroll
      for (int mq = 0; mq < 2; ++mq)
        #pragma unroll
        for (int rr = 0; rr < 4; ++rr)
          *(u16*)(x_l + (size_t)(32 * mh + 16 * mq + 4 * lq + rr) * XP +
                  (64 * v + 16 * n + l15) * 2) = f2b(qacc[mq][rr]);
    }
  }
  __syncthreads();

  // ---- Z_full = QR * G (G symmetric; B-rows = output cols); n-outer ----
  f32x4 acc[4][4];
  #pragma unroll
  for (int m = 0; m < 4; ++m)
    #pragma unroll
    for (int n = 0; n < 4; ++n) acc[m][n] = (f32x4)0.f;

  #pragma unroll
  for (int n = 0; n < 4; ++n) {
    u32x4 bg[8];
    #pragma unroll
    for (int kk = 0; kk < 8; ++kk)
      bg[kk] = *(const u32x4*)(gt +
          (size_t)(64 * v + 16 * n + l15) * C_ + 32 * kk + 8 * lq);
    #pragma unroll
    for (int mm = 0; mm < 4; ++mm) {
      u32x4 qa2[8];
      #pragma unroll
      for (int kk = 0; kk < 8; ++kk)
        qa2[kk] = *(const u32x4*)(x_l + (size_t)(16 * mm + l15) * XP +
                                  64 * kk + 16 * lq);
      #pragma unroll
      for (int kk = 0; kk < 8; ++kk)
        acc[mm][n] = mfma16(qa2[kk], bg[kk], acc[mm][n]);
    }
  }

  // ---- S local = QR * rp^T (diagonal tile), causal mask ----
  {
    f32x4 sacc[4];
    #pragma unroll
    for (int m = 0; m < 4; ++m) sacc[m] = (f32x4)0.f;
    u32x4 bs[8];
    #pragma unroll
    for (int kk = 0; kk < 8; ++kk)
      bs[kk] = *(const u32x4*)(rpb +
          (size_t)(t0 + 16 * v + l15) * C_ + 32 * kk + 8 * lq);
    #pragma unroll
    for (int mm = 0; mm < 4; ++mm) {
      u32x4 qa2[8];
      #pragma unroll
      for (int kk = 0; kk < 8; ++kk)
        qa2[kk] = *(const u32x4*)(x_l + (size_t)(16 * mm + l15) * XP +
                                  64 * kk + 16 * lq);
      #pragma unroll
      for (int kk = 0; kk < 8; ++kk)
        sacc[mm] = mfma16(qa2[kk], bs[kk], sacc[mm]);
    }
    #pragma unroll
    for (int m = 0; m < 4; ++m)
      #pragma unroll
      for (int rr = 0; rr < 4; ++rr) {
        int tl = 16 * m + 4 * lq + rr;
        int ul = 16 * v + l15;
        float sv = (ul > tl) ? 0.f : sacc[m][rr];
        *(u16*)(s_l + (size_t)tl * SP + ul * 2) = f2b(sv);
      }
  }
  __syncthreads();  // also guarantees all x_l (QR) reads are complete

  // ---- Z_loc: acc += S * rp ----
  {
    u32x4 sa[4][2];
    #pragma unroll
    for (int m = 0; m < 4; ++m)
      #pragma unroll
      for (int kk = 0; kk < 2; ++kk)
        sa[m][kk] = *(const u32x4*)(s_l + (size_t)(16 * m + l15) * SP +
                                    64 * kk + 16 * lq);
    #pragma unroll
    for (int n = 0; n < 4; ++n)
      #pragma unroll
      for (int kk = 0; kk < 2; ++kk) {
        u32x4 vb = *(const u32x4*)(rtb +
            (size_t)(64 * v + 16 * n + l15) * T_ + t0 + 32 * kk + 8 * lq);
        #pragma unroll
        for (int m = 0; m < 4; ++m)
          acc[m][n] = mfma16(sa[m][kk], vb, acc[m][n]);
      }
  }

  // ---- write Z into x_l (QR dead past the s_l barrier) ----
  #pragma unroll
  for (int m = 0; m < 4; ++m)
    #pragma unroll
    for (int n = 0; n < 4; ++n)
      #pragma unroll
      for (int rr = 0; rr < 4; ++rr)
        *(u16*)(x_l + (size_t)(16 * m + 4 * lq + rr) * XP +
                (64 * v + 16 * n + l15) * 2) = f2b(acc[m][n][rr]);
  __syncthreads();

  // ---- epilogue: O = Z * E^T; n-outer (E loaded once per wave) ----
  f32x4 oa[4][4];
  #pragma unroll
  for (int m = 0; m < 4; ++m)
    #pragma unroll
    for (int n = 0; n < 4; ++n) oa[m][n] = (f32x4)0.f;

  #pragma unroll
  for (int n = 0; n < 4; ++n) {
    u32x4 eb[8];
    #pragma unroll
    for (int kk = 0; kk < 8; ++kk)
      eb[kk] = *(const u32x4*)(eh +
          (size_t)(64 * v + 16 * n + l15) * C_ + 32 * kk + 8 * lq);
    #pragma unroll
    for (int mm = 0; mm < 4; ++mm) {
      u32x4 za[8];
      #pragma unroll
      for (int kk = 0; kk < 8; ++kk)
        za[kk] = *(const u32x4*)(x_l + (size_t)(16 * mm + l15) * XP +
                                 64 * kk + 16 * lq);
      #pragma unroll
      for (int kk = 0; kk < 8; ++kk)
        oa[mm][n] = mfma16(za[kk], eb[kk], oa[mm][n]);
    }
  }

  // ---- h-reduction via f32 atomics (8 head-blocks per element, same XCD) ----
  float* ob = out + ((size_t)b * T_ + t0) * C_;
  #pragma unroll
  for (int m = 0; m < 4; ++m)
    #pragma unroll
    for (int n = 0; n < 4; ++n)
      #pragma unroll
      for (int rr = 0; rr < 4; ++rr)
        atomicAdd(ob + (size_t)(16 * m + 4 * lq + rr) * C_ + 64 * v + 16 * n + l15,
                  oa[m][n][rr]);
}

extern "C" void kernel_launch(void* const* d_in, const int* in_sizes, int n_in,
                              void* d_out, int out_size, void* d_ws, size_t ws_size,
                              hipStream_t stream) {
  (void)ws_size; (void)out_size;
  const float* rp_f = nullptr;
  const float* sm[2] = {nullptr, nullptr};
  int ns = 0;
  for (int i = 0; i < n_in; ++i) {
    if (in_sizes[i] == 2097152) {
      rp_f = (const float*)d_in[i];
    } else if (ns < 2) {
      sm[ns++] = (const float*)d_in[i];
    }
  }
  const float* E_f = sm[0];
  const float* Q_f = sm[1];

  // ws (26 MB): G [0,16M) | rbf [16,20M) | rpT [20,24M) | Qt [24,25M) | E [25,26M)
  const size_t MB = 1024 * 1024;
  u16* G   = (u16*)d_ws;
  u16* rbf = (u16*)((char*)d_ws + 16 * MB);
  u16* rpT = (u16*)((char*)d_ws + 20 * MB);
  u16* qtb = (u16*)((char*)d_ws + 24 * MB);
  u16* ebf = (u16*)((char*)d_ws + 25 * MB);
  float* outf = (float*)d_out;

  k_prep<<<3200, 256, 0, stream>>>(rp_f, E_f, Q_f, rbf, rpT, qtb, ebf, outf);
  k_gram<<<dim3(8, 4, 4), 256, 0, stream>>>(rpT, G);
  k_main<<<dim3(32, 4, 8), 256, 0, stream>>>(rbf, rpT, qtb, ebf, G, outf);
}

// Round 12
// 153.565 us; speedup vs baseline: 38.3065x; 1.2000x over previous
//
#include <hip/hip_runtime.h>
#include <stdint.h>

typedef unsigned short u16;
typedef __attribute__((ext_vector_type(4))) float f32x4;
typedef __attribute__((ext_vector_type(4))) uint32_t u32x4;
typedef __attribute__((ext_vector_type(8))) __bf16 bf16x8;

#define B_ 4
#define H_ 8
#define T_ 2048
#define C_ 256
#define NCH 32   /* 64-row chunks per b */
#define XP 528   /* QR/Z LDS pitch (bytes): 16B-rotated rows */
#define SP 144   /* S LDS pitch (bytes) */

static __device__ __forceinline__ f32x4 mfma16(u32x4 a, u32x4 b, f32x4 c) {
  union { u32x4 u; bf16x8 b; } A, Bb;
  A.u = a; Bb.u = b;
  return __builtin_amdgcn_mfma_f32_16x16x32_bf16(A.b, Bb.b, c, 0, 0, 0);
}
static __device__ __forceinline__ u16 f2b(float f) {
  union { __bf16 h; u16 u; } r; r.h = (__bf16)f; return r.u;
}

// ---- k_prep: rp->bf16 + rp^T + Q^T + E->bf16, one launch (1152 blocks) ----
__global__ __launch_bounds__(256) void k_prep(const float* __restrict__ rp_f,
                                              const float* __restrict__ E_f,
                                              const float* __restrict__ Q_f,
                                              u16* __restrict__ rbf,
                                              u16* __restrict__ rpT,
                                              u16* __restrict__ qtb,
                                              u16* __restrict__ ebf) {
  __shared__ u16 l[64][72];
  const int r = blockIdx.x, tid = threadIdx.x;
  if (r < 512) {  // rp tile: straight bf16 + transposed bf16
    const int b = r >> 7, i0 = ((r >> 5) & 3) * 64, t0 = (r & 31) * 64;
    const int tj = tid & 63, tq = tid >> 6;
    const float* src = rp_f + (size_t)b * T_ * C_;
    u16* rb = rbf + (size_t)b * T_ * C_;
    #pragma unroll
    for (int rr = 0; rr < 16; ++rr) {
      int tl = rr * 4 + tq;
      u16 v = f2b(src[(size_t)(t0 + tl) * C_ + i0 + tj]);
      l[tl][tj] = v;
      rb[(size_t)(t0 + tl) * C_ + i0 + tj] = v;
    }
    __syncthreads();
    u16* dst = rpT + (size_t)b * C_ * T_;
    #pragma unroll
    for (int rr = 0; rr < 16; ++rr) {
      int il = rr * 4 + tq;
      dst[(size_t)(i0 + il) * T_ + t0 + tj] = l[tj][il];
    }
  } else if (r < 640) {  // Q transpose+convert
    const int q = r - 512;
    const int h = q >> 4, i0 = ((q >> 2) & 3) * 64, j0 = (q & 3) * 64;
    const int tj = tid & 63, tq = tid >> 6;
    const float* qh = Q_f + (size_t)h * C_ * C_;
    #pragma unroll
    for (int rr = 0; rr < 16; ++rr) {
      int i = rr * 4 + tq;
      l[i][tj] = f2b(qh[(size_t)(i0 + i) * C_ + j0 + tj]);
    }
    __syncthreads();
    u16* qth = qtb + (size_t)h * C_ * C_;
    #pragma unroll
    for (int rr = 0; rr < 16; ++rr) {
      int j = rr * 4 + tq;
      qth[(size_t)(j0 + j) * C_ + i0 + tj] = l[tj][j];
    }
  } else {  // E convert (512K elems, 512 blocks)
    const int q = r - 640;
    size_t idx = (size_t)q * 256 + tid;
    f32x4 v = ((const f32x4*)E_f)[idx];
    union { u16 h4[4]; uint64_t qq; } p;
    #pragma unroll
    for (int j = 0; j < 4; ++j) p.h4[j] = f2b(v[j]);
    ((uint64_t*)ebf)[idx] = p.qq;
  }
}

// ---- k_gram: G_excl[b][k][i][j] = sum_{u<64k} rp[u][i]*rp[u][j], bf16 ----
__global__ __launch_bounds__(256) void k_gram(const u16* __restrict__ rpT,
                                              u16* __restrict__ G) {
  const int js = blockIdx.x, iq = blockIdx.y, b = blockIdx.z;
  const int tid = threadIdx.x, lane = tid & 63, v = tid >> 6;
  const int l15 = lane & 15, lq = lane >> 4;
  const u16* rtb = rpT + (size_t)b * C_ * T_;
  const int irow = 64 * iq + 16 * v;

  f32x4 acc[2];
  acc[0] = (f32x4)0.f; acc[1] = (f32x4)0.f;

  for (int k = 0; k < NCH; ++k) {
    u16* gk = G + (size_t)(b * NCH + k) * C_ * C_;
    #pragma unroll
    for (int n = 0; n < 2; ++n)
      #pragma unroll
      for (int rr = 0; rr < 4; ++rr)
        gk[(size_t)(irow + 4 * lq + rr) * C_ + 32 * js + 16 * n + l15] =
            f2b(acc[n][rr]);
    u32x4 am[2], bn[2][2];
    #pragma unroll
    for (int kk = 0; kk < 2; ++kk)
      am[kk] = *(const u32x4*)(rtb + (size_t)(irow + l15) * T_ +
                               64 * k + 32 * kk + 8 * lq);
    #pragma unroll
    for (int n = 0; n < 2; ++n)
      #pragma unroll
      for (int kk = 0; kk < 2; ++kk)
        bn[n][kk] = *(const u32x4*)(rtb + (size_t)(32 * js + 16 * n + l15) * T_ +
                                    64 * k + 32 * kk + 8 * lq);
    #pragma unroll
    for (int n = 0; n < 2; ++n)
      #pragma unroll
      for (int kk = 0; kk < 2; ++kk)
        acc[n] = mfma16(am[kk], bn[n][kk], acc[n]);
  }
}

// ---- k_main<MODE>: per (tile, b, hg) over heads {hg, hg+4}.
// MODE 0: plain stores into partial[hg]; MODE 1: atomicAdd into out (fallback).
template <int MODE>
__global__ __launch_bounds__(256, 2) void k_main(const u16* __restrict__ rbf,
                                                 const u16* __restrict__ rpT,
                                                 const u16* __restrict__ qtb,
                                                 const u16* __restrict__ ebf,
                                                 const u16* __restrict__ G,
                                                 float* __restrict__ part,
                                                 float* __restrict__ out) {
  __shared__ __align__(16) char x_l[64 * XP];  // QR, then Z
  __shared__ __align__(16) char s_l[64 * SP];  // local S

  const int tile = blockIdx.x, b = blockIdx.y, hg = blockIdx.z;
  const int t0 = tile * 64;
  const int tid = threadIdx.x, lane = tid & 63, v = tid >> 6;
  const int l15 = lane & 15, lq = lane >> 4;

  const u16* rpb = rbf + (size_t)b * T_ * C_;
  const u16* rtb = rpT + (size_t)b * C_ * T_;
  const u16* gt  = G + (size_t)(b * NCH + tile) * C_ * C_;

  f32x4 oa[4][4];
  #pragma unroll
  for (int m = 0; m < 4; ++m)
    #pragma unroll
    for (int n = 0; n < 4; ++n) oa[m][n] = (f32x4)0.f;

  for (int hh = 0; hh < 2; ++hh) {
    const int h = hg + 4 * hh;
    const u16* qth = qtb + (size_t)h * C_ * C_;
    const u16* eh  = ebf + (size_t)h * C_ * C_;

    // ---- QR[64 t][256 j]; wave v owns j in [64v, 64v+64) ----
    #pragma unroll
    for (int mh = 0; mh < 2; ++mh) {
      u32x4 am[2][8];
      #pragma unroll
      for (int mq = 0; mq < 2; ++mq)
        #pragma unroll
        for (int kk = 0; kk < 8; ++kk)
          am[mq][kk] = *(const u32x4*)(rpb +
              (size_t)(t0 + 32 * mh + 16 * mq + l15) * C_ + 32 * kk + 8 * lq);
      #pragma unroll
      for (int n = 0; n < 4; ++n) {
        f32x4 qacc[2];
        qacc[0] = (f32x4)0.f; qacc[1] = (f32x4)0.f;
        #pragma unroll
        for (int kk = 0; kk < 8; ++kk) {
          u32x4 bq = *(const u32x4*)(qth +
              (size_t)(64 * v + 16 * n + l15) * C_ + 32 * kk + 8 * lq);
          qacc[0] = mfma16(am[0][kk], bq, qacc[0]);
          qacc[1] = mfma16(am[1][kk], bq, qacc[1]);
        }
        #pragma unroll
        for (int mq = 0; mq < 2; ++mq)
          #pragma unroll
          for (int rr = 0; rr < 4; ++rr)
            *(u16*)(x_l + (size_t)(32 * mh + 16 * mq + 4 * lq + rr) * XP +
                    (64 * v + 16 * n + l15) * 2) = f2b(qacc[mq][rr]);
      }
    }
    __syncthreads();

    // ---- Z_full = QR * G (n-outer: G fragments loaded once) ----
    f32x4 acc[4][4];
    #pragma unroll
    for (int m = 0; m < 4; ++m)
      #pragma unroll
      for (int n = 0; n < 4; ++n) acc[m][n] = (f32x4)0.f;

    #pragma unroll
    for (int n = 0; n < 4; ++n) {
      u32x4 bg[8];
      #pragma unroll
      for (int kk = 0; kk < 8; ++kk)
        bg[kk] = *(const u32x4*)(gt +
            (size_t)(64 * v + 16 * n + l15) * C_ + 32 * kk + 8 * lq);
      #pragma unroll
      for (int mm = 0; mm < 4; ++mm) {
        u32x4 qa2[8];
        #pragma unroll
        for (int kk = 0; kk < 8; ++kk)
          qa2[kk] = *(const u32x4*)(x_l + (size_t)(16 * mm + l15) * XP +
                                    64 * kk + 16 * lq);
        #pragma unroll
        for (int kk = 0; kk < 8; ++kk)
          acc[mm][n] = mfma16(qa2[kk], bg[kk], acc[mm][n]);
      }
    }

    // ---- S local = QR * rp^T (diagonal tile), causal mask ----
    {
      f32x4 sacc[4];
      #pragma unroll
      for (int m = 0; m < 4; ++m) sacc[m] = (f32x4)0.f;
      u32x4 bs[8];
      #pragma unroll
      for (int kk = 0; kk < 8; ++kk)
        bs[kk] = *(const u32x4*)(rpb +
            (size_t)(t0 + 16 * v + l15) * C_ + 32 * kk + 8 * lq);
      #pragma unroll
      for (int mm = 0; mm < 4; ++mm) {
        u32x4 qa2[8];
        #pragma unroll
        for (int kk = 0; kk < 8; ++kk)
          qa2[kk] = *(const u32x4*)(x_l + (size_t)(16 * mm + l15) * XP +
                                    64 * kk + 16 * lq);
        #pragma unroll
        for (int kk = 0; kk < 8; ++kk)
          sacc[mm] = mfma16(qa2[kk], bs[kk], sacc[mm]);
      }
      #pragma unroll
      for (int m = 0; m < 4; ++m)
        #pragma unroll
        for (int rr = 0; rr < 4; ++rr) {
          int tl = 16 * m + 4 * lq + rr;
          int ul = 16 * v + l15;
          float sv = (ul > tl) ? 0.f : sacc[m][rr];
          *(u16*)(s_l + (size_t)tl * SP + ul * 2) = f2b(sv);
        }
    }
    __syncthreads();  // all x_l reads complete; s_l visible

    // ---- Z_loc: acc += S * rp ----
    {
      u32x4 sa[4][2];
      #pragma unroll
      for (int m = 0; m < 4; ++m)
        #pragma unroll
        for (int kk = 0; kk < 2; ++kk)
          sa[m][kk] = *(const u32x4*)(s_l + (size_t)(16 * m + l15) * SP +
                                      64 * kk + 16 * lq);
      #pragma unroll
      for (int n = 0; n < 4; ++n)
        #pragma unroll
        for (int kk = 0; kk < 2; ++kk) {
          u32x4 vb = *(const u32x4*)(rtb +
              (size_t)(64 * v + 16 * n + l15) * T_ + t0 + 32 * kk + 8 * lq);
          #pragma unroll
          for (int m = 0; m < 4; ++m)
            acc[m][n] = mfma16(sa[m][kk], vb, acc[m][n]);
        }
    }

    // ---- write Z into x_l (QR dead) ----
    #pragma unroll
    for (int m = 0; m < 4; ++m)
      #pragma unroll
      for (int n = 0; n < 4; ++n)
        #pragma unroll
        for (int rr = 0; rr < 4; ++rr)
          *(u16*)(x_l + (size_t)(16 * m + 4 * lq + rr) * XP +
                  (64 * v + 16 * n + l15) * 2) = f2b(acc[m][n][rr]);
    __syncthreads();

    // ---- epilogue: oa += Z * E^T (n-outer, E loaded once) ----
    #pragma unroll
    for (int n = 0; n < 4; ++n) {
      u32x4 eb[8];
      #pragma unroll
      for (int kk = 0; kk < 8; ++kk)
        eb[kk] = *(const u32x4*)(eh +
            (size_t)(64 * v + 16 * n + l15) * C_ + 32 * kk + 8 * lq);
      #pragma unroll
      for (int mm = 0; mm < 4; ++mm) {
        u32x4 za[8];
        #pragma unroll
        for (int kk = 0; kk < 8; ++kk)
          za[kk] = *(const u32x4*)(x_l + (size_t)(16 * mm + l15) * XP +
                                   64 * kk + 16 * lq);
        #pragma unroll
        for (int kk = 0; kk < 8; ++kk)
          oa[mm][n] = mfma16(za[kk], eb[kk], oa[mm][n]);
      }
    }
    __syncthreads();  // x_l free before next head's QR writes
  }

  // ---- writeout ----
  if (MODE == 0) {
    float* pb = part + ((size_t)(hg * B_ + b) * T_ + t0) * C_;
    #pragma unroll
    for (int m = 0; m < 4; ++m)
      #pragma unroll
      for (int n = 0; n < 4; ++n)
        #pragma unroll
        for (int rr = 0; rr < 4; ++rr)
          pb[(size_t)(16 * m + 4 * lq + rr) * C_ + 64 * v + 16 * n + l15] =
              oa[m][n][rr];
  } else {
    float* ob = out + ((size_t)b * T_ + t0) * C_;
    #pragma unroll
    for (int m = 0; m < 4; ++m)
      #pragma unroll
      for (int n = 0; n < 4; ++n)
        #pragma unroll
        for (int rr = 0; rr < 4; ++rr)
          atomicAdd(ob + (size_t)(16 * m + 4 * lq + rr) * C_ +
                        64 * v + 16 * n + l15,
                    oa[m][n][rr]);
  }
}

// ---- k_final: out = p0 + p1 + p2 + p3 (f32x4 vectorized) ----
__global__ __launch_bounds__(256) void k_final(const float* __restrict__ part,
                                               float* __restrict__ out) {
  const size_t idx = (size_t)blockIdx.x * 256 + threadIdx.x;
  const size_t N = (size_t)B_ * T_ * C_ / 4;
  const f32x4* p = (const f32x4*)part;
  f32x4 s = p[idx] + p[N + idx] + p[2 * N + idx] + p[3 * N + idx];
  ((f32x4*)out)[idx] = s;
}

extern "C" void kernel_launch(void* const* d_in, const int* in_sizes, int n_in,
                              void* d_out, int out_size, void* d_ws, size_t ws_size,
                              hipStream_t stream) {
  (void)out_size;
  const float* rp_f = nullptr;
  const float* sm[2] = {nullptr, nullptr};
  int ns = 0;
  for (int i = 0; i < n_in; ++i) {
    if (in_sizes[i] == 2097152) {
      rp_f = (const float*)d_in[i];
    } else if (ns < 2) {
      sm[ns++] = (const float*)d_in[i];
    }
  }
  const float* E_f = sm[0];
  const float* Q_f = sm[1];

  // ws: G [0,16M) | rbf [16,20M) | rpT [20,24M) | Qt [24,25M) | E [25,26M)
  //     | partials f32 [26,58M)  (4 x B x T x C)
  const size_t MB = 1024 * 1024;
  u16* G    = (u16*)d_ws;
  u16* rbf  = (u16*)((char*)d_ws + 16 * MB);
  u16* rpT  = (u16*)((char*)d_ws + 20 * MB);
  u16* qtb  = (u16*)((char*)d_ws + 24 * MB);
  u16* ebf  = (u16*)((char*)d_ws + 25 * MB);
  float* part = (float*)((char*)d_ws + 26 * MB);
  float* outf = (float*)d_out;

  k_prep<<<1152, 256, 0, stream>>>(rp_f, E_f, Q_f, rbf, rpT, qtb, ebf);
  k_gram<<<dim3(8, 4, 4), 256, 0, stream>>>(rpT, G);
  if (ws_size >= 58 * MB) {
    k_main<0><<<dim3(32, 4, 4), 256, 0, stream>>>(rbf, rpT, qtb, ebf, G, part,
                                                  nullptr);
    k_final<<<2048, 256, 0, stream>>>(part, outf);
  } else {  // fallback: zero + atomics (round-11 semantics)
    hipMemsetAsync(outf, 0, (size_t)B_ * T_ * C_ * sizeof(float), stream);
    k_main<1><<<dim3(32, 4, 4), 256, 0, stream>>>(rbf, rpT, qtb, ebf, G,
                                                  nullptr, outf);
  }
}